// Round 2
// baseline (3124.286 us; speedup 1.0000x reference)
//
#include <hip/hip_runtime.h>
#include <cstdint>

// ---------------------------------------------------------------------------
// Red-black SOR Laplace solver, persistent-kernel formulation, f64 internal.
// Grid: padded label volume (2 vols of 66^3 concatenated) = 132 x 66 x 66.
// Only gray-matter (label==1) voxels update; sink (label==3) fixed at 1.
// Iterate: black half-sweep, red half-sweep, dv = sum|adj|; stop when
// !(dv >= 0.05 && it <= 500)  (reference jax.lax.while_loop semantics).
// f64 internally: the harness golden ("ref=np") is a high-precision
// recomputation; the clean f64 dv trajectory crosses 0.05 deterministically
// (f32 crossing is rounding-noise-delayed by ~4 iters — round-1 evidence).
// ---------------------------------------------------------------------------

#define NBLK 64
#define NTHR 256

constexpr int NI = 132, NJ = 66, NK = 66;
constexpr int NTOT = NI * NJ * NK;            // 574992
constexpr int RB   = (NTOT + NBLK - 1) / NBLK; // 8985 voxels per block
constexpr int SC   = (RB + NTHR - 1) / NTHR;   // 36 voxels per thread (build)
constexpr int CAP  = 3072;                     // per-color per-block list cap
constexpr int NOUT = 2 * 64 * 64 * 64;         // 524288 lap elements

__global__ void sor_init_ctrl(unsigned* ctrl) { ctrl[0] = 0u; ctrl[1] = 0u; }

// padded flat coords -> original image flat index, or -1 if pad voxel
__device__ __forceinline__ int pad_label_idx(int ii, int jj, int kk) {
  int b  = (ii >= 66) ? 1 : 0;
  int pz = ii - 66 * b;
  if (pz < 1 || pz > 64 || jj < 1 || jj > 64 || kk < 1 || kk > 64) return -1;
  return ((b * 64 + (pz - 1)) * 64 + (jj - 1)) * 64 + (kk - 1);
}

__global__ __launch_bounds__(NTHR, 1)
void sor_main(const float* __restrict__ img, double* __restrict__ x,
              double* __restrict__ partials, unsigned* __restrict__ ctrl,
              float* __restrict__ out) {
  __shared__ unsigned short lsB[CAP], lsR[CAP];
  __shared__ unsigned scn[2][NTHR];
  __shared__ unsigned totB, totR;
  __shared__ double red[NTHR];
  __shared__ double sh_dv;

  const int tid = threadIdx.x, bid = blockIdx.x;
  const int base = bid * RB;
  const int end  = (NTOT < base + RB) ? NTOT : (base + RB);

  // ---- build phase: init x, classify voxels, build per-block LDS lists ----
  int s0 = base + tid * SC;
  int s1 = (s0 + SC < end) ? (s0 + SC) : end;
  unsigned cb = 0, cr = 0;
  for (int i = s0; i < s1; ++i) {
    int ii = i / (NJ * NK);
    int r  = i - ii * (NJ * NK);
    int jj = r / NK;
    int kk = r - jj * NK;
    int li = pad_label_idx(ii, jj, kk);
    float L = (li >= 0) ? img[li] : 0.0f;
    x[i] = (L == 3.0f) ? 1.0 : 0.0;
    if (L == 1.0f) {
      if (((ii + jj + kk) & 1) == 0) cb++; else cr++;
    }
  }
  scn[0][tid] = cb; scn[1][tid] = cr;
  __syncthreads();
  if (tid == 0) {
    unsigned aB = 0, aR = 0;
    for (int t = 0; t < NTHR; ++t) {
      unsigned b2 = scn[0][t]; scn[0][t] = aB; aB += b2;
      unsigned r2 = scn[1][t]; scn[1][t] = aR; aR += r2;
    }
    totB = aB; totR = aR;
  }
  __syncthreads();
  unsigned pB = scn[0][tid], pR = scn[1][tid];
  for (int i = s0; i < s1; ++i) {
    int ii = i / (NJ * NK);
    int r  = i - ii * (NJ * NK);
    int jj = r / NK;
    int kk = r - jj * NK;
    int li = pad_label_idx(ii, jj, kk);
    float L = (li >= 0) ? img[li] : 0.0f;
    if (L == 1.0f) {
      unsigned short off = (unsigned short)(i - base);
      if (((ii + jj + kk) & 1) == 0) { if (pB < CAP) lsB[pB] = off; pB++; }
      else                           { if (pR < CAP) lsR[pR] = off; pR++; }
    }
  }
  __syncthreads();
  const int nbl = (totB < CAP) ? (int)totB : CAP;
  const int nrl = (totR < CAP) ? (int)totR : CAP;

  // ---- grid barrier: monotonic generation counter, agent scope ----
  unsigned bar_t = 0;
  #define GRID_BARRIER() do {                                                  \
    __syncthreads();                                                           \
    if (tid == 0) {                                                            \
      bar_t++;                                                                 \
      unsigned a_ = __hip_atomic_fetch_add(&ctrl[0], 1u, __ATOMIC_ACQ_REL,     \
                                           __HIP_MEMORY_SCOPE_AGENT);          \
      if (a_ == NBLK - 1) {                                                    \
        __hip_atomic_store(&ctrl[0], 0u, __ATOMIC_RELAXED,                     \
                           __HIP_MEMORY_SCOPE_AGENT);                          \
        __hip_atomic_fetch_add(&ctrl[1], 1u, __ATOMIC_RELEASE,                 \
                               __HIP_MEMORY_SCOPE_AGENT);                      \
      } else {                                                                 \
        while (__hip_atomic_load(&ctrl[1], __ATOMIC_RELAXED,                   \
                                 __HIP_MEMORY_SCOPE_AGENT) < bar_t)            \
          __builtin_amdgcn_s_sleep(1);                                         \
        __builtin_amdgcn_fence(__ATOMIC_ACQUIRE, "agent");                     \
      }                                                                        \
    }                                                                          \
    __syncthreads();                                                           \
  } while (0)

  const double WOPT = 2.0 / (1.0 + 3.14159265358979323846 / 66.0);

  GRID_BARRIER();  // x fully initialized, lists ready

  int it = 0;
  double dv_tot = 0.0;
  for (;;) {
    double acc = 0.0;
    // ---- black half-sweep (reads pre-sweep values: neighbors are red) ----
    for (int p = tid; p < nbl; p += NTHR) {
      const int fi = base + (int)lsB[p];
      double xi = x[fi];
      double nb = ((((x[fi - 1] + x[fi + 1]) + x[fi - NK]) + x[fi + NK])
                  + x[fi - NJ * NK]) + x[fi + NJ * NK];
      double adj = (WOPT * (nb - 6.0 * xi)) / 6.0;
      x[fi] = xi + adj;
      acc += fabs(adj);
    }
    GRID_BARRIER();  // black writes visible everywhere
    // ---- red half-sweep (reads updated black values) ----
    for (int p = tid; p < nrl; p += NTHR) {
      const int fi = base + (int)lsR[p];
      double xi = x[fi];
      double nb = ((((x[fi - 1] + x[fi + 1]) + x[fi - NK]) + x[fi + NK])
                  + x[fi - NJ * NK]) + x[fi + NJ * NK];
      double adj = (WOPT * (nb - 6.0 * xi)) / 6.0;
      x[fi] = xi + adj;
      acc += fabs(adj);
    }
    // ---- block reduction of dv (deterministic tree) ----
    red[tid] = acc;
    __syncthreads();
    for (int s = NTHR / 2; s > 0; s >>= 1) {
      if (tid < s) red[tid] += red[tid + s];
      __syncthreads();
    }
    if (tid == 0) partials[bid] = red[0];
    GRID_BARRIER();  // red writes + partials visible everywhere
    if (tid == 0) {
      double s = 0.0;
      for (int i2 = 0; i2 < NBLK; ++i2) s += partials[i2];
      sh_dv = s;
    }
    __syncthreads();
    dv_tot = sh_dv;
    ++it;
    // reference: continue iff (it==0) || (dv >= 0.05 && it <= 500); it>=1 here
    if (!((dv_tot >= 0.05) && (it <= 500))) break;
  }

  // ---- epilogue: crop padding, write lap + iters + dv ----
  const int gtid = bid * NTHR + tid;
  const int NTTH = NBLK * NTHR;
  for (int o = gtid; o < NOUT; o += NTTH) {
    int b   = o >> 18;
    int rem = o & 262143;
    int zi  = rem >> 12;
    int yi  = (rem >> 6) & 63;
    int xi2 = rem & 63;
    int fi  = ((b * 66 + zi + 1) * 66 + (yi + 1)) * 66 + (xi2 + 1);
    out[o] = (float)x[fi];
  }
  if (gtid == 0) {
    out[NOUT]     = (float)it;
    out[NOUT + 1] = (float)dv_tot;
  }
  #undef GRID_BARRIER
}

extern "C" void kernel_launch(void* const* d_in, const int* in_sizes, int n_in,
                              void* d_out, int out_size, void* d_ws, size_t ws_size,
                              hipStream_t stream) {
  const float* img = (const float*)d_in[0];
  float* out = (float*)d_out;
  char* ws = (char*)d_ws;
  double*   x        = (double*)ws;
  double*   partials = (double*)(ws + (size_t)NTOT * 8);
  unsigned* ctrl     = (unsigned*)(ws + (size_t)NTOT * 8 + (size_t)NBLK * 8);

  sor_init_ctrl<<<1, 1, 0, stream>>>(ctrl);
  sor_main<<<NBLK, NTHR, 0, stream>>>(img, x, partials, ctrl, out);
}

// Round 3
// 2696.753 us; speedup vs baseline: 1.1585x; 1.1585x over previous
//
#include <hip/hip_runtime.h>
#include <cstdint>

// ---------------------------------------------------------------------------
// Red-black SOR Laplace solver, persistent kernel, f64 internal state.
// Padded grid 132 x 66 x 66 (two 66^3 volumes concatenated along axis 0).
// Only gray-matter (label==1) voxels update; sink (label==3) fixed at 1.
// Stop when !(dv >= 0.05 && it <= 500)   [jax.lax.while_loop semantics]
//
// Coherence design: all cross-block data (x, partials) uses agent-scope
// relaxed atomics (sc1 path, bypasses non-coherent L1/L2). Grid barrier is
// fence-free: s_waitcnt vmcnt(0) before arrival guarantees sc1 stores are
// at the LLC; spinners' subsequent sc1 loads read the LLC directly, and
// per-wave in-order issue means they can't start before the spin exits.
// This removes the buffer_inv L2 invalidation that round-2's ACQ_REL
// barrier paid (3.2 MB refetch/iter, measured via FETCH_SIZE).
// ---------------------------------------------------------------------------

#define NBLK 64
#define NTHR 256

constexpr int NI = 132, NJ = 66, NK = 66;
constexpr int NTOT = NI * NJ * NK;             // 574992
constexpr int RB   = (NTOT + NBLK - 1) / NBLK; // 8985 voxels per block
constexpr int SC   = (RB + NTHR - 1) / NTHR;   // 36 voxels per thread (build)
constexpr int CAP  = 3072;                     // per-color per-block list cap
constexpr int NOUT = 2 * 64 * 64 * 64;         // 524288 lap elements

// ctrl layout (u32): [0] = generation; [32 + 32*c] = arrival counter c (0..7)
// counters on distinct 128B cachelines to reduce same-line RMW serialization.
constexpr int CTRL_WORDS = 512;

__global__ void sor_init_ctrl(unsigned* ctrl) {
  for (int i = threadIdx.x; i < CTRL_WORDS; i += blockDim.x) ctrl[i] = 0u;
}

__device__ __forceinline__ double cload(const double* p) {
  return __hip_atomic_load(p, __ATOMIC_RELAXED, __HIP_MEMORY_SCOPE_AGENT);
}
__device__ __forceinline__ void cstore(double* p, double v) {
  __hip_atomic_store(p, v, __ATOMIC_RELAXED, __HIP_MEMORY_SCOPE_AGENT);
}

// padded flat coords -> original image flat index, or -1 if pad voxel
__device__ __forceinline__ int pad_label_idx(int ii, int jj, int kk) {
  int b  = (ii >= 66) ? 1 : 0;
  int pz = ii - 66 * b;
  if (pz < 1 || pz > 64 || jj < 1 || jj > 64 || kk < 1 || kk > 64) return -1;
  return ((b * 64 + (pz - 1)) * 64 + (jj - 1)) * 64 + (kk - 1);
}

__global__ __launch_bounds__(NTHR, 1)
void sor_main(const float* __restrict__ img, double* __restrict__ x,
              double* __restrict__ partials, unsigned* __restrict__ ctrl,
              float* __restrict__ out) {
  __shared__ unsigned short lsB[CAP], lsR[CAP];
  __shared__ unsigned scn[2][NTHR];
  __shared__ unsigned totB, totR;
  __shared__ double redw[4];
  __shared__ double sh_dv;

  const int tid = threadIdx.x, bid = blockIdx.x;
  const int base = bid * RB;
  const int end  = (NTOT < base + RB) ? NTOT : (base + RB);

  // ---- build phase: init x, classify voxels, build per-block LDS lists ----
  int s0 = base + tid * SC;
  int s1 = (s0 + SC < end) ? (s0 + SC) : end;
  unsigned cb = 0, cr = 0;
  for (int i = s0; i < s1; ++i) {
    int ii = i / (NJ * NK);
    int r  = i - ii * (NJ * NK);
    int jj = r / NK;
    int kk = r - jj * NK;
    int li = pad_label_idx(ii, jj, kk);
    float L = (li >= 0) ? img[li] : 0.0f;
    cstore(&x[i], (L == 3.0f) ? 1.0 : 0.0);
    if (L == 1.0f) {
      if (((ii + jj + kk) & 1) == 0) cb++; else cr++;
    }
  }
  scn[0][tid] = cb; scn[1][tid] = cr;
  __syncthreads();
  if (tid == 0) {
    unsigned aB = 0, aR = 0;
    for (int t = 0; t < NTHR; ++t) {
      unsigned b2 = scn[0][t]; scn[0][t] = aB; aB += b2;
      unsigned r2 = scn[1][t]; scn[1][t] = aR; aR += r2;
    }
    totB = aB; totR = aR;
  }
  __syncthreads();
  unsigned pB = scn[0][tid], pR = scn[1][tid];
  for (int i = s0; i < s1; ++i) {
    int ii = i / (NJ * NK);
    int r  = i - ii * (NJ * NK);
    int jj = r / NK;
    int kk = r - jj * NK;
    int li = pad_label_idx(ii, jj, kk);
    float L = (li >= 0) ? img[li] : 0.0f;
    if (L == 1.0f) {
      unsigned short off = (unsigned short)(i - base);
      if (((ii + jj + kk) & 1) == 0) { if (pB < CAP) lsB[pB] = off; pB++; }
      else                           { if (pR < CAP) lsR[pR] = off; pR++; }
    }
  }
  __syncthreads();
  const int nbl = (totB < CAP) ? (int)totB : CAP;
  const int nrl = (totR < CAP) ? (int)totR : CAP;

  // ---- fence-free grid barrier (monotonic generation, 8 arrival lines) ----
  unsigned bar_t = 0;
  #define GRID_BARRIER() do {                                                  \
    __syncthreads();                                                           \
    if (tid == 0) {                                                            \
      bar_t++;                                                                 \
      asm volatile("s_waitcnt vmcnt(0) lgkmcnt(0)" ::: "memory");              \
      __hip_atomic_fetch_add(&ctrl[32 + 32 * (bid & 7)], 1u,                   \
                             __ATOMIC_RELAXED, __HIP_MEMORY_SCOPE_AGENT);      \
      if (bid == 0) {                                                          \
        for (;;) {                                                             \
          unsigned s_ = 0;                                                     \
          for (int c_ = 0; c_ < 8; ++c_)                                       \
            s_ += __hip_atomic_load(&ctrl[32 + 32 * c_], __ATOMIC_RELAXED,     \
                                    __HIP_MEMORY_SCOPE_AGENT);                 \
          if (s_ >= (unsigned)NBLK * bar_t) break;                             \
          __builtin_amdgcn_s_sleep(1);                                         \
        }                                                                      \
        __hip_atomic_store(&ctrl[0], bar_t, __ATOMIC_RELAXED,                  \
                           __HIP_MEMORY_SCOPE_AGENT);                          \
      } else {                                                                 \
        while (__hip_atomic_load(&ctrl[0], __ATOMIC_RELAXED,                   \
                                 __HIP_MEMORY_SCOPE_AGENT) < bar_t)            \
          __builtin_amdgcn_s_sleep(1);                                         \
      }                                                                        \
    }                                                                          \
    __syncthreads();                                                           \
  } while (0)

  const double WOPT = 2.0 / (1.0 + 3.14159265358979323846 / 66.0);

  GRID_BARRIER();  // x fully initialized everywhere, lists ready

  int it = 0;
  double dv_tot = 0.0;
  for (;;) {
    double acc = 0.0;
    // ---- black half-sweep (reads pre-sweep values: neighbors are red) ----
    for (int p = tid; p < nbl; p += NTHR) {
      const int fi = base + (int)lsB[p];
      double xi = cload(&x[fi]);
      double nb = ((((cload(&x[fi - 1]) + cload(&x[fi + 1]))
                   + cload(&x[fi - NK])) + cload(&x[fi + NK]))
                   + cload(&x[fi - NJ * NK])) + cload(&x[fi + NJ * NK]);
      double adj = (WOPT * (nb - 6.0 * xi)) / 6.0;
      cstore(&x[fi], xi + adj);
      acc += fabs(adj);
    }
    GRID_BARRIER();  // black writes visible everywhere
    // ---- red half-sweep (reads updated black values) ----
    for (int p = tid; p < nrl; p += NTHR) {
      const int fi = base + (int)lsR[p];
      double xi = cload(&x[fi]);
      double nb = ((((cload(&x[fi - 1]) + cload(&x[fi + 1]))
                   + cload(&x[fi - NK])) + cload(&x[fi + NK]))
                   + cload(&x[fi - NJ * NK])) + cload(&x[fi + NJ * NK]);
      double adj = (WOPT * (nb - 6.0 * xi)) / 6.0;
      cstore(&x[fi], xi + adj);
      acc += fabs(adj);
    }
    // ---- per-block dv reduce: wave butterfly (fixed order) + 4-way sum ----
    double a = acc;
    #pragma unroll
    for (int m = 32; m >= 1; m >>= 1) a += __shfl_xor(a, m, 64);
    if ((tid & 63) == 0) redw[tid >> 6] = a;
    __syncthreads();
    if (tid == 0) cstore(&partials[bid], ((redw[0] + redw[1]) + redw[2]) + redw[3]);
    GRID_BARRIER();  // red writes + partials visible everywhere
    // ---- global dv: every block sums 64 partials in the same fixed order --
    if (tid < 64) {
      double g = cload(&partials[tid]);
      #pragma unroll
      for (int m = 32; m >= 1; m >>= 1) g += __shfl_xor(g, m, 64);
      if (tid == 0) sh_dv = g;
    }
    __syncthreads();
    dv_tot = sh_dv;
    ++it;
    // reference: continue iff (it==0) || (dv >= 0.05 && it <= 500); it>=1 here
    if (!((dv_tot >= 0.05) && (it <= 500))) break;
  }

  // ---- epilogue: crop padding, write lap + iters + dv ----
  const int gtid = bid * NTHR + tid;
  const int NTTH = NBLK * NTHR;
  for (int o = gtid; o < NOUT; o += NTTH) {
    int b   = o >> 18;
    int rem = o & 262143;
    int zi  = rem >> 12;
    int yi  = (rem >> 6) & 63;
    int xi2 = rem & 63;
    int fi  = ((b * 66 + zi + 1) * 66 + (yi + 1)) * 66 + (xi2 + 1);
    out[o] = (float)cload(&x[fi]);
  }
  if (gtid == 0) {
    out[NOUT]     = (float)it;
    out[NOUT + 1] = (float)dv_tot;
  }
  #undef GRID_BARRIER
}

extern "C" void kernel_launch(void* const* d_in, const int* in_sizes, int n_in,
                              void* d_out, int out_size, void* d_ws, size_t ws_size,
                              hipStream_t stream) {
  const float* img = (const float*)d_in[0];
  float* out = (float*)d_out;
  char* ws = (char*)d_ws;
  double*   x        = (double*)ws;
  double*   partials = (double*)(ws + (size_t)NTOT * 8);
  unsigned* ctrl     = (unsigned*)(ws + (size_t)NTOT * 8 + (size_t)NBLK * 8);

  sor_init_ctrl<<<1, 256, 0, stream>>>(ctrl);
  sor_main<<<NBLK, NTHR, 0, stream>>>(img, x, partials, ctrl, out);
}

// Round 4
// 2206.698 us; speedup vs baseline: 1.4158x; 1.2221x over previous
//
#include <hip/hip_runtime.h>
#include <cstdint>

// ---------------------------------------------------------------------------
// Red-black SOR Laplace solver, persistent kernel, f64, ONE barrier/iter.
// Padded grid 132 x 66 x 66. Block b owns plane z=b (4356 voxels).
// Ping-pong x buffers: iteration t reads buf[t&1], writes buf[(t+1)&1].
// Black-sweep adjustments are recomputed redundantly for planes z-1,z,z+1
// into LDS (bit-exact: same formula, same f64 inputs as the owning block),
// so the red sweep needs no mid-iteration global sync. The single grid
// barrier sits at end-of-iteration; dv partials are parity-buffered.
// Stop when !(dv >= 0.05 && it <= 500)  [jax.lax.while_loop semantics].
// ---------------------------------------------------------------------------

#define NBLK 132
#define NTHR 256

constexpr int NJK   = 66;
constexpr int PLANE = 66 * 66;          // 4356
constexpr int NI    = 132;
constexpr int NTOT  = NI * PLANE;       // 574992
constexpr int CAPL  = PLANE / 2;        // 2178 (exact max per color per plane)
constexpr int NOUT  = 2 * 64 * 64 * 64; // 524288
constexpr int CTRL_WORDS = 512;         // 16 lines x 32 words (128 B apart)
constexpr int PPAD  = 160;              // partials stride per parity

__global__ void sor_init_ctrl(unsigned* ctrl) {
  for (int i = threadIdx.x; i < CTRL_WORDS; i += blockDim.x) ctrl[i] = 0u;
}

__device__ __forceinline__ double cload(const double* p) {
  return __hip_atomic_load(p, __ATOMIC_RELAXED, __HIP_MEMORY_SCOPE_AGENT);
}
__device__ __forceinline__ void cstore(double* p, double v) {
  __hip_atomic_store(p, v, __ATOMIC_RELAXED, __HIP_MEMORY_SCOPE_AGENT);
}

// padded flat coords -> original image flat index, or -1 if pad voxel
__device__ __forceinline__ int pad_label_idx(int ii, int jj, int kk) {
  int b  = (ii >= 66) ? 1 : 0;
  int pz = ii - 66 * b;
  if (pz < 1 || pz > 64 || jj < 1 || jj > 64 || kk < 1 || kk > 64) return -1;
  return ((b * 64 + (pz - 1)) * 64 + (jj - 1)) * 64 + (kk - 1);
}

__global__ __launch_bounds__(NTHR, 1)
void sor_main(const float* __restrict__ img, double* __restrict__ x0,
              double* __restrict__ x1, double* __restrict__ partials,
              unsigned* __restrict__ ctrl, float* __restrict__ out) {
  __shared__ double ADJ[3][PLANE];          // 104544 B: black adj, z-1,z,z+1
  __shared__ unsigned short lsB[3][CAPL];   // black lists for planes z-1,z,z+1
  __shared__ unsigned short lsR[CAPL];      // red list, own plane
  __shared__ unsigned scn[NTHR];
  __shared__ unsigned tot;
  __shared__ double redw[4];
  __shared__ double sh_dv;

  const int tid = threadIdx.x, bid = blockIdx.x;
  const int z = bid;

  // ---- init own plane in BOTH buffers; zero ADJ (non-gm entries stay 0) ----
  for (int o = tid; o < PLANE; o += NTHR) {
    int j = o / NJK, k = o - j * NJK;
    int li = pad_label_idx(z, j, k);
    float L = (li >= 0) ? img[li] : 0.0f;
    double v = (L == 3.0f) ? 1.0 : 0.0;
    cstore(&x0[(size_t)z * PLANE + o], v);
    cstore(&x1[(size_t)z * PLANE + o], v);
    ADJ[0][o] = 0.0; ADJ[1][o] = 0.0; ADJ[2][o] = 0.0;
  }

  // ---- build gm lists: black for z-1,z,z+1; red for z (stable o-order) ----
  int cntB[3], cntR = 0;
  const int CH = (PLANE + NTHR - 1) / NTHR;  // 18
  for (int pass = 0; pass < 4; ++pass) {
    const int zz = (pass < 3) ? (z - 1 + pass) : z;
    const int wpar = (pass < 3) ? 0 : 1;
    unsigned short* list = (pass < 3) ? lsB[pass] : lsR;
    const bool ok = (zz >= 0 && zz < NI);
    int c0 = tid * CH;
    int c1 = (c0 + CH < PLANE) ? (c0 + CH) : PLANE;
    unsigned cnt = 0;
    if (ok) {
      for (int o = c0; o < c1; ++o) {
        int j = o / NJK, k = o - j * NJK;
        if (((zz + j + k) & 1) != wpar) continue;
        int li = pad_label_idx(zz, j, k);
        float L = (li >= 0) ? img[li] : 0.0f;
        if (L == 1.0f) cnt++;
      }
    }
    __syncthreads();           // scn free from previous pass
    scn[tid] = cnt;
    __syncthreads();
    if (tid == 0) {
      unsigned a = 0;
      for (int t = 0; t < NTHR; ++t) { unsigned c = scn[t]; scn[t] = a; a += c; }
      tot = a;
    }
    __syncthreads();
    unsigned p = scn[tid];
    if (ok) {
      for (int o = c0; o < c1; ++o) {
        int j = o / NJK, k = o - j * NJK;
        if (((zz + j + k) & 1) != wpar) continue;
        int li = pad_label_idx(zz, j, k);
        float L = (li >= 0) ? img[li] : 0.0f;
        if (L == 1.0f) list[p++] = (unsigned short)o;
      }
    }
    __syncthreads();
    if (pass < 3) cntB[pass] = (int)tot; else cntR = (int)tot;
  }

  // ---- all-poll grid barrier: 16 arrival lines, no generation hop ----
  unsigned bar_t = 0;
  #define GRID_BARRIER() do {                                                  \
    __syncthreads();   /* drains every wave's vmem before s_barrier */         \
    bar_t++;                                                                   \
    if (tid < 64) {                                                            \
      if (tid == 0)                                                            \
        __hip_atomic_fetch_add(&ctrl[32 * (bid & 15)], 1u,                     \
                               __ATOMIC_RELAXED, __HIP_MEMORY_SCOPE_AGENT);    \
      const unsigned tgt = (unsigned)NBLK * bar_t;                             \
      for (;;) {                                                               \
        unsigned v = __hip_atomic_load(&ctrl[32 * (tid & 15)],                 \
                                       __ATOMIC_RELAXED,                       \
                                       __HIP_MEMORY_SCOPE_AGENT);              \
        v += __shfl_xor(v, 1, 64);  v += __shfl_xor(v, 2, 64);                 \
        v += __shfl_xor(v, 4, 64);  v += __shfl_xor(v, 8, 64);                 \
        if (v >= tgt) break;                                                   \
        __builtin_amdgcn_s_sleep(1);                                           \
      }                                                                        \
    }                                                                          \
    __syncthreads();                                                           \
  } while (0)

  const double WOPT = 2.0 / (1.0 + 3.14159265358979323846 / 66.0);

  GRID_BARRIER();  // init of both buffers visible everywhere

  int it = 0;
  double dv_tot = 0.0;
  for (;;) {
    const double* __restrict__ xo = (it & 1) ? x1 : x0;
    double* __restrict__ xn       = (it & 1) ? x0 : x1;
    double acc = 0.0;

    // ---- black adj for planes z-1, z, z+1 (reads xo only; LDS results) ----
    #pragma unroll
    for (int s = 0; s < 3; ++s) {
      const int n = cntB[s];
      const long pb = (long)(z - 1 + s) * PLANE;
      #pragma unroll 4
      for (int p = tid; p < n; p += NTHR) {
        const int o = (int)lsB[s][p];
        const long fi = pb + o;
        double xi = cload(&xo[fi]);
        double nb = ((((cload(&xo[fi - 1]) + cload(&xo[fi + 1]))
                     + cload(&xo[fi - NJK])) + cload(&xo[fi + NJK]))
                     + cload(&xo[fi - PLANE])) + cload(&xo[fi + PLANE]);
        double adj = (WOPT * (nb - 6.0 * xi)) / 6.0;
        ADJ[s][o] = adj;
        if (s == 1) {                       // own plane: commit + dv
          cstore(&xn[fi], xi + adj);
          acc += fabs(adj);
        }
      }
    }
    __syncthreads();  // ADJ complete for red

    // ---- red sweep, own plane: neighbor value = xo[n] + ADJ[n] ----
    {
      const long pb = (long)z * PLANE;
      #pragma unroll 4
      for (int p = tid; p < cntR; p += NTHR) {
        const int o = (int)lsR[p];
        const long fi = pb + o;
        double xi = cload(&xo[fi]);
        double v1 = cload(&xo[fi - 1])     + ADJ[1][o - 1];
        double v2 = cload(&xo[fi + 1])     + ADJ[1][o + 1];
        double v3 = cload(&xo[fi - NJK])   + ADJ[1][o - NJK];
        double v4 = cload(&xo[fi + NJK])   + ADJ[1][o + NJK];
        double v5 = cload(&xo[fi - PLANE]) + ADJ[0][o];
        double v6 = cload(&xo[fi + PLANE]) + ADJ[2][o];
        double nb = ((((v1 + v2) + v3) + v4) + v5) + v6;
        double adj = (WOPT * (nb - 6.0 * xi)) / 6.0;
        cstore(&xn[fi], xi + adj);
        acc += fabs(adj);
      }
    }

    // ---- block dv reduce (fixed order) + parity-buffered publish ----
    double a = acc;
    #pragma unroll
    for (int m = 32; m >= 1; m >>= 1) a += __shfl_xor(a, m, 64);
    if ((tid & 63) == 0) redw[tid >> 6] = a;
    __syncthreads();
    double* pp = partials + (size_t)(it & 1) * PPAD;
    if (tid == 0) cstore(&pp[bid], ((redw[0] + redw[1]) + redw[2]) + redw[3]);

    GRID_BARRIER();  // xn + partials visible everywhere

    // ---- global dv: identical fixed-order reduce in every block ----
    if (tid < 64) {
      double A = cload(&pp[tid]);
      double B = cload(&pp[64 + tid]);
      double C = (tid < NBLK - 128) ? cload(&pp[128 + tid]) : 0.0;
      #pragma unroll
      for (int m = 32; m >= 1; m >>= 1) {
        A += __shfl_xor(A, m, 64);
        B += __shfl_xor(B, m, 64);
        C += __shfl_xor(C, m, 64);
      }
      if (tid == 0) sh_dv = (A + B) + C;
    }
    __syncthreads();
    dv_tot = sh_dv;
    ++it;
    // continue iff (dv >= 0.05 && it <= 500); uniform across all blocks
    if (!((dv_tot >= 0.05) && (it <= 500))) break;
  }

  // ---- epilogue: crop padding from final buffer, write lap + iters + dv ----
  const double* __restrict__ xf = (it & 1) ? x1 : x0;
  const int gtid = bid * NTHR + tid;
  const int NTTH = NBLK * NTHR;
  for (int o = gtid; o < NOUT; o += NTTH) {
    int b   = o >> 18;
    int rem = o & 262143;
    int zi  = rem >> 12;
    int yi  = (rem >> 6) & 63;
    int xi2 = rem & 63;
    long fi = ((long)(b * 66 + zi + 1) * 66 + (yi + 1)) * 66 + (xi2 + 1);
    out[o] = (float)cload(&xf[fi]);
  }
  if (gtid == 0) {
    out[NOUT]     = (float)it;
    out[NOUT + 1] = (float)dv_tot;
  }
  #undef GRID_BARRIER
}

extern "C" void kernel_launch(void* const* d_in, const int* in_sizes, int n_in,
                              void* d_out, int out_size, void* d_ws, size_t ws_size,
                              hipStream_t stream) {
  const float* img = (const float*)d_in[0];
  float* out = (float*)d_out;
  char* ws = (char*)d_ws;
  double*   x0       = (double*)ws;
  double*   x1       = (double*)(ws + (size_t)NTOT * 8);
  double*   partials = (double*)(ws + (size_t)NTOT * 16);
  unsigned* ctrl     = (unsigned*)(ws + (size_t)NTOT * 16 + (size_t)2 * PPAD * 8);

  sor_init_ctrl<<<1, 256, 0, stream>>>(ctrl);
  sor_main<<<NBLK, NTHR, 0, stream>>>(img, x0, x1, partials, ctrl, out);
}

// Round 5
// 1919.700 us; speedup vs baseline: 1.6275x; 1.1495x over previous
//
#include <hip/hip_runtime.h>
#include <cstdint>

// ---------------------------------------------------------------------------
// Red-black SOR Laplace solver, persistent kernel, f64, ONE barrier/iter.
// Padded grid 132 x 66 x 66. Block b owns plane z=b (4356 voxels).
// Ping-pong x buffers: iteration t reads buf[t&1], writes buf[(t+1)&1].
// Black-sweep adjustments are recomputed redundantly for planes z-1,z,z+1
// into LDS (bit-exact vs the owning block), so the red sweep needs no
// mid-iteration global sync. Single grid barrier at end-of-iteration;
// dv partials parity-buffered.  Stop when !(dv >= 0.05 && it <= 500).
// Round 5: NTHR 256->1024 (4x outstanding LLC loads; round-4 counters showed
// the sweep stream limited to ~1 TB/s by wave concurrency, VALUBusy 2%).
// ---------------------------------------------------------------------------

#define NBLK 132
#define NTHR 1024
#define NW   (NTHR / 64)

constexpr int NJK   = 66;
constexpr int PLANE = 66 * 66;          // 4356
constexpr int NI    = 132;
constexpr int NTOT  = NI * PLANE;       // 574992
constexpr int CAPL  = PLANE / 2;        // 2178
constexpr int NOUT  = 2 * 64 * 64 * 64; // 524288
constexpr int CTRL_WORDS = 512;         // 16 lines x 32 words (128 B apart)
constexpr int PPAD  = 160;              // partials stride per parity

__global__ void sor_init_ctrl(unsigned* ctrl) {
  for (int i = threadIdx.x; i < CTRL_WORDS; i += blockDim.x) ctrl[i] = 0u;
}

__device__ __forceinline__ double cload(const double* p) {
  return __hip_atomic_load(p, __ATOMIC_RELAXED, __HIP_MEMORY_SCOPE_AGENT);
}
__device__ __forceinline__ void cstore(double* p, double v) {
  __hip_atomic_store(p, v, __ATOMIC_RELAXED, __HIP_MEMORY_SCOPE_AGENT);
}

// padded flat coords -> original image flat index, or -1 if pad voxel
__device__ __forceinline__ int pad_label_idx(int ii, int jj, int kk) {
  int b  = (ii >= 66) ? 1 : 0;
  int pz = ii - 66 * b;
  if (pz < 1 || pz > 64 || jj < 1 || jj > 64 || kk < 1 || kk > 64) return -1;
  return ((b * 64 + (pz - 1)) * 64 + (jj - 1)) * 64 + (kk - 1);
}

__global__ __launch_bounds__(NTHR, 1)
void sor_main(const float* __restrict__ img, double* __restrict__ x0,
              double* __restrict__ x1, double* __restrict__ partials,
              unsigned* __restrict__ ctrl, float* __restrict__ out) {
  __shared__ double ADJ[3][PLANE];          // 104544 B: black adj, z-1,z,z+1
  __shared__ unsigned short lsB[3][CAPL];   // black lists, planes z-1,z,z+1
  __shared__ unsigned short lsR[CAPL];      // red list, own plane
  __shared__ unsigned wsum[NW], woff[NW];
  __shared__ unsigned tot;
  __shared__ double redw[NW];
  __shared__ double sh_dv;

  const int tid = threadIdx.x, bid = blockIdx.x;
  const int lane = tid & 63, wid = tid >> 6;
  const int z = bid;

  // ---- init own plane in BOTH buffers; zero ADJ ----
  for (int o = tid; o < PLANE; o += NTHR) {
    int j = o / NJK, k = o - j * NJK;
    int li = pad_label_idx(z, j, k);
    float L = (li >= 0) ? img[li] : 0.0f;
    double v = (L == 3.0f) ? 1.0 : 0.0;
    cstore(&x0[(size_t)z * PLANE + o], v);
    cstore(&x1[(size_t)z * PLANE + o], v);
    ADJ[0][o] = 0.0; ADJ[1][o] = 0.0; ADJ[2][o] = 0.0;
  }

  // ---- build gm lists: black for z-1,z,z+1; red for z (stable o-order) ----
  int cntB[3], cntR = 0;
  const int CH = (PLANE + NTHR - 1) / NTHR;
  for (int pass = 0; pass < 4; ++pass) {
    const int zz = (pass < 3) ? (z - 1 + pass) : z;
    const int wpar = (pass < 3) ? 0 : 1;
    unsigned short* list = (pass < 3) ? lsB[pass] : lsR;
    const bool ok = (zz >= 0 && zz < NI);
    int c0 = tid * CH;
    int c1 = (c0 + CH < PLANE) ? (c0 + CH) : PLANE;
    unsigned cnt = 0;
    if (ok) {
      for (int o = c0; o < c1; ++o) {
        int j = o / NJK, k = o - j * NJK;
        if (((zz + j + k) & 1) != wpar) continue;
        int li = pad_label_idx(zz, j, k);
        float L = (li >= 0) ? img[li] : 0.0f;
        if (L == 1.0f) cnt++;
      }
    }
    // hierarchical exclusive scan: wave shfl scan + serial wave-offset scan
    unsigned incl = cnt;
    #pragma unroll
    for (int m = 1; m < 64; m <<= 1) {
      unsigned t = __shfl_up(incl, m, 64);
      if (lane >= m) incl += t;
    }
    __syncthreads();           // wsum/woff free from previous pass
    if (lane == 63) wsum[wid] = incl;
    __syncthreads();
    if (tid == 0) {
      unsigned a = 0;
      for (int w = 0; w < NW; ++w) { unsigned c = wsum[w]; woff[w] = a; a += c; }
      tot = a;
    }
    __syncthreads();
    unsigned p = (incl - cnt) + woff[wid];
    if (ok) {
      for (int o = c0; o < c1; ++o) {
        int j = o / NJK, k = o - j * NJK;
        if (((zz + j + k) & 1) != wpar) continue;
        int li = pad_label_idx(zz, j, k);
        float L = (li >= 0) ? img[li] : 0.0f;
        if (L == 1.0f) list[p++] = (unsigned short)o;
      }
    }
    __syncthreads();
    if (pass < 3) cntB[pass] = (int)tot; else cntR = (int)tot;
  }

  // ---- grid barrier: 16 arrival lines; 16 poll lanes, butterfly sum ----
  unsigned bar_t = 0;
  #define GRID_BARRIER() do {                                                  \
    __syncthreads();                                                           \
    bar_t++;                                                                   \
    if (tid == 0)                                                              \
      __hip_atomic_fetch_add(&ctrl[32 * (bid & 15)], 1u,                       \
                             __ATOMIC_RELAXED, __HIP_MEMORY_SCOPE_AGENT);      \
    if (tid < 16) {                                                            \
      const unsigned tgt = (unsigned)NBLK * bar_t;                             \
      for (;;) {                                                               \
        unsigned v = __hip_atomic_load(&ctrl[32 * tid], __ATOMIC_RELAXED,      \
                                       __HIP_MEMORY_SCOPE_AGENT);              \
        v += __shfl_xor(v, 1, 64);  v += __shfl_xor(v, 2, 64);                 \
        v += __shfl_xor(v, 4, 64);  v += __shfl_xor(v, 8, 64);                 \
        if (v >= tgt) break;                                                   \
        __builtin_amdgcn_s_sleep(1);                                           \
      }                                                                        \
    }                                                                          \
    __syncthreads();                                                           \
  } while (0)

  const double WOPT = 2.0 / (1.0 + 3.14159265358979323846 / 66.0);

  GRID_BARRIER();  // init of both buffers visible everywhere

  int it = 0;
  double dv_tot = 0.0;
  for (;;) {
    const double* __restrict__ xo = (it & 1) ? x1 : x0;
    double* __restrict__ xn       = (it & 1) ? x0 : x1;
    double acc = 0.0;

    // ---- black adj for planes z-1, z, z+1 (reads xo only; LDS results) ----
    #pragma unroll
    for (int s = 0; s < 3; ++s) {
      const int n = cntB[s];
      const long pb = (long)(z - 1 + s) * PLANE;
      for (int p = tid; p < n; p += NTHR) {
        const int o = (int)lsB[s][p];
        const long fi = pb + o;
        double xi = cload(&xo[fi]);
        double nb = ((((cload(&xo[fi - 1]) + cload(&xo[fi + 1]))
                     + cload(&xo[fi - NJK])) + cload(&xo[fi + NJK]))
                     + cload(&xo[fi - PLANE])) + cload(&xo[fi + PLANE]);
        double adj = (WOPT * (nb - 6.0 * xi)) / 6.0;
        ADJ[s][o] = adj;
        if (s == 1) {                       // own plane: commit + dv
          cstore(&xn[fi], xi + adj);
          acc += fabs(adj);
        }
      }
    }
    __syncthreads();  // ADJ complete for red

    // ---- red sweep, own plane: neighbor value = xo[n] + ADJ[n] ----
    {
      const long pb = (long)z * PLANE;
      for (int p = tid; p < cntR; p += NTHR) {
        const int o = (int)lsR[p];
        const long fi = pb + o;
        double xi = cload(&xo[fi]);
        double v1 = cload(&xo[fi - 1])     + ADJ[1][o - 1];
        double v2 = cload(&xo[fi + 1])     + ADJ[1][o + 1];
        double v3 = cload(&xo[fi - NJK])   + ADJ[1][o - NJK];
        double v4 = cload(&xo[fi + NJK])   + ADJ[1][o + NJK];
        double v5 = cload(&xo[fi - PLANE]) + ADJ[0][o];
        double v6 = cload(&xo[fi + PLANE]) + ADJ[2][o];
        double nb = ((((v1 + v2) + v3) + v4) + v5) + v6;
        double adj = (WOPT * (nb - 6.0 * xi)) / 6.0;
        cstore(&xn[fi], xi + adj);
        acc += fabs(adj);
      }
    }

    // ---- block dv reduce (fixed order) + parity-buffered publish ----
    double a = acc;
    #pragma unroll
    for (int m = 32; m >= 1; m >>= 1) a += __shfl_xor(a, m, 64);
    if (lane == 0) redw[wid] = a;
    __syncthreads();
    double* pp = partials + (size_t)(it & 1) * PPAD;
    if (tid == 0) {
      double s = redw[0];
      #pragma unroll
      for (int w = 1; w < NW; ++w) s += redw[w];
      cstore(&pp[bid], s);
    }

    GRID_BARRIER();  // xn + partials visible everywhere

    // ---- global dv: identical fixed-order reduce in every block ----
    if (tid < 64) {
      double A = cload(&pp[tid]);
      double B = cload(&pp[64 + tid]);
      double C = (tid < NBLK - 128) ? cload(&pp[128 + tid]) : 0.0;
      #pragma unroll
      for (int m = 32; m >= 1; m >>= 1) {
        A += __shfl_xor(A, m, 64);
        B += __shfl_xor(B, m, 64);
        C += __shfl_xor(C, m, 64);
      }
      if (tid == 0) sh_dv = (A + B) + C;
    }
    __syncthreads();
    dv_tot = sh_dv;
    ++it;
    // continue iff (dv >= 0.05 && it <= 500); uniform across all blocks
    if (!((dv_tot >= 0.05) && (it <= 500))) break;
  }

  // ---- epilogue: crop padding from final buffer, write lap + iters + dv ----
  const double* __restrict__ xf = (it & 1) ? x1 : x0;
  const int gtid = bid * NTHR + tid;
  const int NTTH = NBLK * NTHR;
  for (int o = gtid; o < NOUT; o += NTTH) {
    int b   = o >> 18;
    int rem = o & 262143;
    int zi  = rem >> 12;
    int yi  = (rem >> 6) & 63;
    int xi2 = rem & 63;
    long fi = ((long)(b * 66 + zi + 1) * 66 + (yi + 1)) * 66 + (xi2 + 1);
    out[o] = (float)cload(&xf[fi]);
  }
  if (gtid == 0) {
    out[NOUT]     = (float)it;
    out[NOUT + 1] = (float)dv_tot;
  }
  #undef GRID_BARRIER
}

extern "C" void kernel_launch(void* const* d_in, const int* in_sizes, int n_in,
                              void* d_out, int out_size, void* d_ws, size_t ws_size,
                              hipStream_t stream) {
  const float* img = (const float*)d_in[0];
  float* out = (float*)d_out;
  char* ws = (char*)d_ws;
  double*   x0       = (double*)ws;
  double*   x1       = (double*)(ws + (size_t)NTOT * 8);
  double*   partials = (double*)(ws + (size_t)NTOT * 16);
  unsigned* ctrl     = (unsigned*)(ws + (size_t)NTOT * 16 + (size_t)2 * PPAD * 8);

  sor_init_ctrl<<<1, 256, 0, stream>>>(ctrl);
  sor_main<<<NBLK, NTHR, 0, stream>>>(img, x0, x1, partials, ctrl, out);
}